// Round 1
// baseline (122.072 us; speedup 1.0000x reference)
//
#include <hip/hip_runtime.h>

// LocalMean: 5x5 box filter, stride 1, reflect padding (edge not duplicated).
// Input/Output: float32, (16, 3, 1024, 1024). Memory-bound: ~403 MB total
// traffic -> ~64 us roofline at 6.3 TB/s achievable.

constexpr int W  = 1024;
constexpr int H  = 1024;
constexpr int RS = 32;   // output rows per block strip

__global__ __launch_bounds__(256)
void box5_kernel(const float* __restrict__ in, float* __restrict__ out) {
    const int t     = threadIdx.x;        // 0..255, covers full row: 4 px each
    const int strip = blockIdx.x;         // 0..H/RS-1
    const int plane = blockIdx.y;         // 0..47  (16*3 planes)

    const size_t poff = (size_t)plane * (size_t)W * (size_t)H;
    const float* img = in  + poff;
    float*       o   = out + poff;

    const int x0   = t << 2;              // first of 4 columns this thread owns
    const int base = strip * RS;          // first output row of this strip

    float4 h0 = make_float4(0.f, 0.f, 0.f, 0.f);
    float4 h1 = h0, h2 = h0, h3 = h0, h4 = h0;
    const float inv25 = 1.0f / 25.0f;

    // Safe (always in-bounds, 16B-aligned) neighbor-chunk offsets; edge
    // threads get a dummy load whose lanes are overridden by reflect selects.
    const int lx = (t != 0)   ? x0 - 4 : x0;
    const int rx = (t != 255) ? x0 + 4 : x0;

    for (int cnt = 0; cnt < RS + 4; ++cnt) {
        const int r  = base - 2 + cnt;                      // input row (virtual)
        const int rr = (r < 0) ? -r : ((r >= H) ? 2 * H - 2 - r : r);  // reflect
        const float* row = img + (size_t)rr * W;

        const float4 v  = *(const float4*)(row + x0);
        const float4 lv = *(const float4*)(row + lx);
        const float4 rv = *(const float4*)(row + rx);

        // elements x0-2..x0+5 with horizontal reflect at image edges
        const float em2 = (t != 0)   ? lv.z : v.z;   // x=-2 -> 2
        const float em1 = (t != 0)   ? lv.w : v.y;   // x=-1 -> 1
        const float e4  = (t != 255) ? rv.x : v.z;   // x=1024 -> 1022
        const float e5  = (t != 255) ? rv.y : v.y;   // x=1025 -> 1021

        // 4 horizontal 5-tap sums, sharing partials
        const float c12 = v.y + v.z;                 // e1+e2
        const float c123 = c12 + v.w;                // e1+e2+e3
        float4 hn;
        hn.x = (em2 + em1) + v.x + c12;
        hn.y = em1 + v.x + c123;
        hn.z = (v.x + c123) + e4;
        hn.w = c123 + (e4 + e5);

        // rotate 5-row window
        h0 = h1; h1 = h2; h2 = h3; h3 = h4; h4 = hn;

        if (cnt >= 4) {
            const int y = r - 2;                      // output row
            float4 s;
            s.x = ((h0.x + h1.x) + (h2.x + h3.x)) + h4.x;
            s.y = ((h0.y + h1.y) + (h2.y + h3.y)) + h4.y;
            s.z = ((h0.z + h1.z) + (h2.z + h3.z)) + h4.z;
            s.w = ((h0.w + h1.w) + (h2.w + h3.w)) + h4.w;
            s.x *= inv25; s.y *= inv25; s.z *= inv25; s.w *= inv25;
            *(float4*)(o + (size_t)y * W + x0) = s;
        }
    }
}

extern "C" void kernel_launch(void* const* d_in, const int* in_sizes, int n_in,
                              void* d_out, int out_size, void* d_ws, size_t ws_size,
                              hipStream_t stream) {
    const float* in  = (const float*)d_in[0];
    float*       out = (float*)d_out;

    dim3 grid(H / RS, 16 * 3);   // 32 strips x 48 planes = 1536 blocks
    dim3 block(256);
    box5_kernel<<<grid, block, 0, stream>>>(in, out);
}

// Round 3
// 70.642 us; speedup vs baseline: 1.7280x; 1.7280x over previous
//
#include <hip/hip_runtime.h>

// LocalMean: 5x5 box filter, stride 1, reflect padding (edge not duplicated).
// Input/Output: float32, (16, 3, 1024, 1024).
// R1: 122us @ 2.2TB/s, Occupancy 45% -> latency/occupancy-bound.
// R2: RS=16 (3072 blocks, 8 resident/CU = 32 waves), nontemporal stores so
//     the 197MB output stream doesn't evict the L3-resident input.
//     (R2 fix: __builtin_nontemporal_store needs a clang ext_vector_type,
//      not HIP's float4 class.)

typedef float f32x4 __attribute__((ext_vector_type(4)));

constexpr int W  = 1024;
constexpr int H  = 1024;
constexpr int RS = 16;   // output rows per block strip

__global__ __launch_bounds__(256, 8)   // 8 waves/EU -> 8 blocks/CU, VGPR<=64
void box5_kernel(const float* __restrict__ in, float* __restrict__ out) {
    const int t     = threadIdx.x;        // 0..255, covers full row: 4 px each
    const int strip = blockIdx.x;         // 0..H/RS-1
    const int plane = blockIdx.y;         // 0..47  (16*3 planes)

    const size_t poff = (size_t)plane * (size_t)W * (size_t)H;
    const float* img = in  + poff;
    float*       o   = out + poff;

    const int x0   = t << 2;              // first of 4 columns this thread owns
    const int base = strip * RS;          // first output row of this strip

    f32x4 h0 = (f32x4)(0.f);
    f32x4 h1 = h0, h2 = h0, h3 = h0, h4 = h0;
    const float inv25 = 1.0f / 25.0f;

    // Safe (always in-bounds, 16B-aligned) neighbor-chunk offsets; edge
    // threads get a dummy load whose lanes are overridden by reflect selects.
    const int lx = (t != 0)   ? x0 - 4 : x0;
    const int rx = (t != 255) ? x0 + 4 : x0;

    for (int cnt = 0; cnt < RS + 4; ++cnt) {
        const int r  = base - 2 + cnt;                      // input row (virtual)
        const int rr = (r < 0) ? -r : ((r >= H) ? 2 * H - 2 - r : r);  // reflect
        const float* row = img + (size_t)rr * W;

        const f32x4 v  = *(const f32x4*)(row + x0);
        const f32x4 lv = *(const f32x4*)(row + lx);
        const f32x4 rv = *(const f32x4*)(row + rx);

        // elements x0-2..x0+5 with horizontal reflect at image edges
        const float em2 = (t != 0)   ? lv.z : v.z;   // x=-2 -> 2
        const float em1 = (t != 0)   ? lv.w : v.y;   // x=-1 -> 1
        const float e4  = (t != 255) ? rv.x : v.z;   // x=1024 -> 1022
        const float e5  = (t != 255) ? rv.y : v.y;   // x=1025 -> 1021

        // 4 horizontal 5-tap sums, sharing partials
        const float c12 = v.y + v.z;                 // e1+e2
        const float c123 = c12 + v.w;                // e1+e2+e3
        f32x4 hn;
        hn.x = (em2 + em1) + v.x + c12;
        hn.y = em1 + v.x + c123;
        hn.z = (v.x + c123) + e4;
        hn.w = c123 + (e4 + e5);

        // rotate 5-row window
        h0 = h1; h1 = h2; h2 = h3; h3 = h4; h4 = hn;

        if (cnt >= 4) {
            const int y = r - 2;                      // output row
            f32x4 s = ((h0 + h1) + (h2 + h3)) + h4;
            s *= inv25;
            __builtin_nontemporal_store(s, (f32x4*)(o + (size_t)y * W + x0));
        }
    }
}

extern "C" void kernel_launch(void* const* d_in, const int* in_sizes, int n_in,
                              void* d_out, int out_size, void* d_ws, size_t ws_size,
                              hipStream_t stream) {
    const float* in  = (const float*)d_in[0];
    float*       out = (float*)d_out;

    dim3 grid(H / RS, 16 * 3);   // 64 strips x 48 planes = 3072 blocks
    dim3 block(256);
    box5_kernel<<<grid, block, 0, stream>>>(in, out);
}

// Round 4
// 69.957 us; speedup vs baseline: 1.7450x; 1.0098x over previous
//
#include <hip/hip_runtime.h>

// LocalMean: 5x5 box filter, stride 1, reflect padding (edge not duplicated).
// Input/Output: float32, (16, 3, 1024, 1024).
// R1: 122us @ 2.2TB/s, Occupancy 45% -> latency/occupancy-bound.
// R3: RS=16 + nontemporal stores -> 70.6us, Occ 68%. FETCH stuck at 125MB
//     (L3 is memory-side: write stream allocates, evicts input) -> per-replay
//     HBM ~325MB, floor ~51us. Limiter now: 3072 blocks vs 2048 resident =
//     1.5 rounds, round 2 half-empty (matches Occ 68%).
// R4: exact-fill grid: 2048 blocks (8/CU x 256CU), each owns 24 flattened
//     (plane,row) output rows; segments split at plane boundaries (47/2048
//     blocks pay one extra 4-row pipeline warmup). One round, no tail.

typedef float f32x4 __attribute__((ext_vector_type(4)));

constexpr int W       = 1024;
constexpr int H       = 1024;
constexpr int NPLANES = 16 * 3;
constexpr int RPB     = 24;                        // output rows per block
constexpr int NBLK    = (NPLANES * H) / RPB;       // 2048 exactly

__global__ __launch_bounds__(256, 8)   // 8 blocks/CU -> 32 waves/CU
void box5_kernel(const float* __restrict__ in, float* __restrict__ out) {
    const int t  = threadIdx.x;        // 0..255, covers full row: 4 px each
    const int x0 = t << 2;
    // Safe (always in-bounds, 16B-aligned) neighbor-chunk offsets; edge
    // threads get a dummy load whose lanes are overridden by reflect selects.
    const int lx = (t != 0)   ? x0 - 4 : x0;
    const int rx = (t != 255) ? x0 + 4 : x0;
    const float inv25 = 1.0f / 25.0f;

    int g         = blockIdx.x * RPB;  // flattened global output row
    int rows_left = RPB;

    while (rows_left > 0) {
        const int plane = g >> 10;           // g / H
        const int r0    = g & (H - 1);       // g % H
        int seg = H - r0; if (seg > rows_left) seg = rows_left;

        const size_t poff = (size_t)plane * (size_t)(W * H);
        const float* img = in  + poff;
        float*       o   = out + poff;

        f32x4 h0 = (f32x4)(0.f);
        f32x4 h1 = h0, h2 = h0, h3 = h0, h4 = h0;

        for (int cnt = 0; cnt < seg + 4; ++cnt) {
            const int r  = r0 - 2 + cnt;                                 // virtual input row
            const int rr = (r < 0) ? -r : ((r >= H) ? 2 * H - 2 - r : r); // reflect
            const float* row = img + (size_t)rr * W;

            const f32x4 v  = *(const f32x4*)(row + x0);
            const f32x4 lv = *(const f32x4*)(row + lx);
            const f32x4 rv = *(const f32x4*)(row + rx);

            // elements x0-2..x0+5 with horizontal reflect at image edges
            const float em2 = (t != 0)   ? lv.z : v.z;   // x=-2 -> 2
            const float em1 = (t != 0)   ? lv.w : v.y;   // x=-1 -> 1
            const float e4  = (t != 255) ? rv.x : v.z;   // x=1024 -> 1022
            const float e5  = (t != 255) ? rv.y : v.y;   // x=1025 -> 1021

            // 4 horizontal 5-tap sums, sharing partials
            const float c12  = v.y + v.z;
            const float c123 = c12 + v.w;
            f32x4 hn;
            hn.x = (em2 + em1) + v.x + c12;
            hn.y = em1 + v.x + c123;
            hn.z = (v.x + c123) + e4;
            hn.w = c123 + (e4 + e5);

            // rotate 5-row window
            h0 = h1; h1 = h2; h2 = h3; h3 = h4; h4 = hn;

            if (cnt >= 4) {
                const int y = r - 2;                      // output row
                f32x4 s = ((h0 + h1) + (h2 + h3)) + h4;
                s *= inv25;
                __builtin_nontemporal_store(s, (f32x4*)(o + (size_t)y * W + x0));
            }
        }

        g += seg; rows_left -= seg;
    }
}

extern "C" void kernel_launch(void* const* d_in, const int* in_sizes, int n_in,
                              void* d_out, int out_size, void* d_ws, size_t ws_size,
                              hipStream_t stream) {
    const float* in  = (const float*)d_in[0];
    float*       out = (float*)d_out;

    box5_kernel<<<dim3(NBLK), dim3(256), 0, stream>>>(in, out);
}